// Round 1
// baseline (261.795 us; speedup 1.0000x reference)
//
#include <hip/hip_runtime.h>
#include <hip/hip_bf16.h>

#define N_NODES 10000
#define KNEI    30
#define DIM     128
#define EDGES   (N_NODES * KNEI)

typedef __attribute__((ext_vector_type(4))) float  f32x4;
typedef __attribute__((ext_vector_type(8))) __bf16 bf16x8;
typedef __attribute__((ext_vector_type(4))) __bf16 bf16x4;

// packed bf16 weight offsets in d_ws (element units)
#define OFF_AW1 0        // 384x128 -> 12*8 tiles
#define OFF_AW2 49152    // 128x128 -> 4*8
#define OFF_AW3 65536    // 128x4 (padded to 16) -> 4*1
#define OFF_NW1 67584    // 256x128 -> 8*8
#define OFF_NW2 100352   // 128x128
#define OFF_NW3 116736   // 128x128
#define WTOTAL  133120

// Pack W[k][n] (f32) into MFMA A-fragment order, bf16:
// tile = kt*(Ntiles)+nt ; within tile: lane holds n = nt*16+(lane&15),
// k = kt*32+(lane>>4)*8+i, 8 contiguous bf16 per lane (one dwordx4).
__global__ __launch_bounds__(256) void repack_w(const float* __restrict__ src,
                                                __bf16* __restrict__ dst,
                                                int Kd, int Nsrc, int Ntiles) {
    int t = blockIdx.x * 256 + threadIdx.x;
    int total = (Kd >> 5) * Ntiles * 512;
    if (t >= total) return;
    int i    = t & 7;
    int lane = (t >> 3) & 63;
    int tile = t >> 9;
    int nt = tile % Ntiles;
    int kt = tile / Ntiles;
    int k = kt * 32 + ((lane >> 4) << 3) + i;
    int n = nt * 16 + (lane & 15);
    float v = (n < Nsrc) ? src[k * Nsrc + n] : 0.f;
    dst[t] = (__bf16)v;
}

// ---- fused GNN layer kernel ----
// One workgroup = 2 nodes (60 edges, padded to 64 rows). 4 waves; wave w owns
// output features [w*32, w*32+32). Computes Y^T = W^T X^T via MFMA so the
// accumulator lands with 4 consecutive n per lane at fixed edge-row m.

__device__ __forceinline__ void mm_part(f32x4 acc[2][4], const __bf16* __restrict__ wp,
                                        const __bf16* x, int sx, int ksteps,
                                        int wv, int lane) {
    const int mrow = lane & 15;
    const int kgrp = lane >> 4;
    for (int kt = 0; kt < ksteps; ++kt) {
        bf16x8 a0 = *reinterpret_cast<const bf16x8*>(wp + ((kt * 8 + wv * 2 + 0) * 64 + lane) * 8);
        bf16x8 a1 = *reinterpret_cast<const bf16x8*>(wp + ((kt * 8 + wv * 2 + 1) * 64 + lane) * 8);
        const int kb = kt * 32 + kgrp * 8;
#pragma unroll
        for (int mf = 0; mf < 4; ++mf) {
            bf16x8 b = *reinterpret_cast<const bf16x8*>(x + (mf * 16 + mrow) * sx + kb);
            acc[0][mf] = __builtin_amdgcn_mfma_f32_16x16x32_bf16(a0, b, acc[0][mf], 0, 0, 0);
            acc[1][mf] = __builtin_amdgcn_mfma_f32_16x16x32_bf16(a1, b, acc[1][mf], 0, 0, 0);
        }
    }
}

// actmode: 0 = relu, 1 = gelu(erf), 2 = none
__device__ __forceinline__ void store_act(f32x4 acc[2][4], const float* __restrict__ bias,
                                          __bf16* y, int sy, int actmode,
                                          int wv, int lane) {
    const int mrow = lane & 15;
    const int kgrp = lane >> 4;
#pragma unroll
    for (int nf = 0; nf < 2; ++nf) {
        const int nb = wv * 32 + nf * 16 + kgrp * 4;
        const float* bp = bias + nb;
#pragma unroll
        for (int mf = 0; mf < 4; ++mf) {
            bf16x4 pk;
#pragma unroll
            for (int r = 0; r < 4; ++r) {
                float v = acc[nf][mf][r] + bp[r];
                if (actmode == 0)      v = fmaxf(v, 0.f);
                else if (actmode == 1) v = 0.5f * v * (1.f + erff(v * 0.70710678118f));
                pk[r] = (__bf16)v;
            }
            *reinterpret_cast<bf16x4*>(y + (mf * 16 + mrow) * sy + nb) = pk;
        }
    }
}

__device__ __forceinline__ bf16x4 cvt4(float4 v) {
    bf16x4 r;
    r[0] = (__bf16)v.x; r[1] = (__bf16)v.y; r[2] = (__bf16)v.z; r[3] = (__bf16)v.w;
    return r;
}

#define ZERO_ACC(A)                                   \
    do {                                              \
        _Pragma("unroll")                             \
        for (int _n = 0; _n < 2; ++_n)                \
            _Pragma("unroll")                         \
            for (int _m = 0; _m < 4; ++_m)            \
                A[_n][_m] = (f32x4){0.f, 0.f, 0.f, 0.f}; \
    } while (0)

__global__ __launch_bounds__(256, 2) void gnn_fused(
    const float* __restrict__ h, const float* __restrict__ e, const int* __restrict__ eidx,
    const float* __restrict__ ab1, const float* __restrict__ ab2, const float* __restrict__ ab3,
    const float* __restrict__ nb1, const float* __restrict__ nb2, const float* __restrict__ nb3,
    const float* __restrict__ thw, const __bf16* __restrict__ wp, float* __restrict__ out) {

    // padded strides (+8 bf16) -> ~2-way LDS bank aliasing (free)
    __shared__ __bf16 sXB[64 * 264];   // [m][0:128)=e, [128:256)=hj
    __shared__ __bf16 sHI[64 * 136];   // hi; reused as att-Y2 and node-Y2
    __shared__ __bf16 sA1[64 * 136];   // att-Y1 / node-Y1 / V
    __shared__ float  sLog[64 * 4];    // logits [m][h]
    __shared__ float  sSM[8 * 2];      // (max, 1/sum) per (node, h)
    __shared__ float  sPre[2][128];    // aggregated pre-projection

    const int tid  = threadIdx.x;
    const int wv   = tid >> 6;
    const int lane = tid & 63;
    const int node0 = blockIdx.x * 2;
    const long ebase = (long)node0 * KNEI;

    // ---- stage e, hj, hi rows (f32 -> bf16); pad rows 60..63 = 0 ----
#pragma unroll
    for (int c = 0; c < 8; ++c) {
        int idx = c * 256 + tid;
        int m  = idx >> 5;   // row 0..63
        int jv = idx & 31;   // float4 column
        float4 ev = make_float4(0.f, 0.f, 0.f, 0.f), hjv = ev, hiv = ev;
        if (m < 2 * KNEI) {
            long ge = ebase + m;
            ev  = *reinterpret_cast<const float4*>(e + ge * DIM + jv * 4);
            int dstn = eidx[EDGES + ge];
            hjv = *reinterpret_cast<const float4*>(h + (long)dstn * DIM + jv * 4);
            int srcn = eidx[ge];
            hiv = *reinterpret_cast<const float4*>(h + (long)srcn * DIM + jv * 4);
        }
        *reinterpret_cast<bf16x4*>(&sXB[m * 264 + jv * 4])       = cvt4(ev);
        *reinterpret_cast<bf16x4*>(&sXB[m * 264 + 128 + jv * 4]) = cvt4(hjv);
        *reinterpret_cast<bf16x4*>(&sHI[m * 136 + jv * 4])       = cvt4(hiv);
    }
    __syncthreads();

    f32x4 acc[2][4];

    // ---- att layer 1: [hi | e | hj] (K=384) -> relu -> sA1 ----
    ZERO_ACC(acc);
    mm_part(acc, wp + OFF_AW1,         sHI, 136, 4, wv, lane);  // k 0..127 (hi)
    mm_part(acc, wp + OFF_AW1 + 16384, sXB, 264, 8, wv, lane);  // k 128..383 (e|hj)
    store_act(acc, ab1, sA1, 136, 0, wv, lane);
    __syncthreads();

    // ---- att layer 2: sA1 -> relu -> sHI ----
    ZERO_ACC(acc);
    mm_part(acc, wp + OFF_AW2, sA1, 136, 4, wv, lane);
    store_act(acc, ab2, sHI, 136, 0, wv, lane);
    __syncthreads();

    // ---- att layer 3 (logits, 4 heads) on wave 0 ----
    if (wv == 0) {
        f32x4 a3[4];
#pragma unroll
        for (int mf = 0; mf < 4; ++mf) a3[mf] = (f32x4){0.f, 0.f, 0.f, 0.f};
        const int mrow = lane & 15, kgrp = lane >> 4;
        for (int kt = 0; kt < 4; ++kt) {
            bf16x8 aa = *reinterpret_cast<const bf16x8*>(wp + OFF_AW3 + (kt * 64 + lane) * 8);
            int kb = kt * 32 + kgrp * 8;
#pragma unroll
            for (int mf = 0; mf < 4; ++mf) {
                bf16x8 b = *reinterpret_cast<const bf16x8*>(sHI + (mf * 16 + mrow) * 136 + kb);
                a3[mf] = __builtin_amdgcn_mfma_f32_16x16x32_bf16(aa, b, a3[mf], 0, 0, 0);
            }
        }
        if (kgrp == 0) {  // lanes 0..15 hold h=0..3 in regs 0..3
            const float s = 0.17677669529f;  // 1/sqrt(32)
            float b0 = ab3[0], b1 = ab3[1], b2 = ab3[2], b3 = ab3[3];
#pragma unroll
            for (int mf = 0; mf < 4; ++mf) {
                float4 lg;
                lg.x = (a3[mf][0] + b0) * s;
                lg.y = (a3[mf][1] + b1) * s;
                lg.z = (a3[mf][2] + b2) * s;
                lg.w = (a3[mf][3] + b3) * s;
                *reinterpret_cast<float4*>(&sLog[(mf * 16 + mrow) * 4]) = lg;
            }
        }
    }

    // ---- node layer 1: [e | hj] (K=256) -> gelu -> sA1 ----
    ZERO_ACC(acc);
    mm_part(acc, wp + OFF_NW1, sXB, 264, 8, wv, lane);
    store_act(acc, nb1, sA1, 136, 1, wv, lane);
    __syncthreads();   // also: logits done before sHI overwritten below

    // ---- node layer 2: sA1 -> gelu -> sHI ----
    ZERO_ACC(acc);
    mm_part(acc, wp + OFF_NW2, sA1, 136, 4, wv, lane);
    store_act(acc, nb2, sHI, 136, 1, wv, lane);
    __syncthreads();

    // softmax precompute (max, 1/sum) per (node, head); overlaps node L3
    if (tid < 8) {
        int nd = tid >> 2, hh = tid & 3;
        float mx = -1e30f;
        for (int k = 0; k < KNEI; ++k) mx = fmaxf(mx, sLog[(nd * KNEI + k) * 4 + hh]);
        float sum = 0.f;
        for (int k = 0; k < KNEI; ++k) sum += __expf(sLog[(nd * KNEI + k) * 4 + hh] - mx);
        sSM[tid * 2]     = mx;
        sSM[tid * 2 + 1] = 1.f / sum;
    }

    // ---- node layer 3: sHI -> (+bias, no act) -> V in sA1 ----
    ZERO_ACC(acc);
    mm_part(acc, wp + OFF_NW3, sHI, 136, 4, wv, lane);
    store_act(acc, nb3, sA1, 136, 2, wv, lane);
    __syncthreads();

    // ---- softmax-weighted aggregation: out_pre[node][d] ----
    {
        int nd = tid >> 7, dd = tid & 127, hh = dd >> 5;
        float mx  = sSM[(nd * 4 + hh) * 2];
        float inv = sSM[(nd * 4 + hh) * 2 + 1];
        float a = 0.f;
        for (int k = 0; k < KNEI; ++k) {
            int m = nd * KNEI + k;
            float wgt = __expf(sLog[m * 4 + hh] - mx) * inv;
            a += wgt * (float)sA1[m * 136 + dd];
        }
        sPre[nd][dd] = a;
    }
    __syncthreads();

    // ---- final projection: out = pre @ to_h_w (f32 vector ALU) ----
    {
        int nd = tid >> 7, dd = tid & 127;
        float o = 0.f;
        for (int d = 0; d < DIM; ++d) o += sPre[nd][d] * thw[d * DIM + dd];
        out[(long)(node0 + nd) * DIM + dd] = o;
    }
}

extern "C" void kernel_launch(void* const* d_in, const int* in_sizes, int n_in,
                              void* d_out, int out_size, void* d_ws, size_t ws_size,
                              hipStream_t stream) {
    const float* h   = (const float*)d_in[0];
    const float* e   = (const float*)d_in[1];
    const int*   ei  = (const int*)d_in[2];
    const float* aw1 = (const float*)d_in[3];
    const float* ab1 = (const float*)d_in[4];
    const float* aw2 = (const float*)d_in[5];
    const float* ab2 = (const float*)d_in[6];
    const float* aw3 = (const float*)d_in[7];
    const float* ab3 = (const float*)d_in[8];
    const float* nw1 = (const float*)d_in[9];
    const float* nb1 = (const float*)d_in[10];
    const float* nw2 = (const float*)d_in[11];
    const float* nb2 = (const float*)d_in[12];
    const float* nw3 = (const float*)d_in[13];
    const float* nb3 = (const float*)d_in[14];
    const float* thw = (const float*)d_in[15];
    float* out = (float*)d_out;
    __bf16* wp = (__bf16*)d_ws;

    // weight repack (f32 -> bf16 MFMA-fragment order), ~266 KB into d_ws
    repack_w<<<192, 256, 0, stream>>>(aw1, wp + OFF_AW1, 384, 128, 8);
    repack_w<<<64,  256, 0, stream>>>(aw2, wp + OFF_AW2, 128, 128, 8);
    repack_w<<<8,   256, 0, stream>>>(aw3, wp + OFF_AW3, 128, 4,   1);
    repack_w<<<128, 256, 0, stream>>>(nw1, wp + OFF_NW1, 256, 128, 8);
    repack_w<<<64,  256, 0, stream>>>(nw2, wp + OFF_NW2, 128, 128, 8);
    repack_w<<<64,  256, 0, stream>>>(nw3, wp + OFF_NW3, 128, 128, 8);

    gnn_fused<<<N_NODES / 2, 256, 0, stream>>>(h, e, ei, ab1, ab2, ab3,
                                               nb1, nb2, nb3, thw, wp, out);
}

// Round 2
// 205.365 us; speedup vs baseline: 1.2748x; 1.2748x over previous
//
#include <hip/hip_runtime.h>
#include <hip/hip_bf16.h>

#define N_NODES 10000
#define KNEI    30
#define DIM     128
#define EDGES   (N_NODES * KNEI)

typedef __attribute__((ext_vector_type(4))) float  f32x4;
typedef __attribute__((ext_vector_type(8))) __bf16 bf16x8;
typedef __attribute__((ext_vector_type(4))) __bf16 bf16x4;

// packed bf16 weight offsets in d_ws (element units)
#define OFF_AW1 0        // 384x128 -> 12*8 tiles
#define OFF_AW2 49152    // 128x128 -> 4*8
#define OFF_AW3 65536    // 128x4 (padded to 16) -> 4*1
#define OFF_NW1 67584    // 256x128 -> 8*8
#define OFF_NW2 100352   // 128x128
#define OFF_NW3 116736   // 128x128
#define WTOTAL  133120

// Pack W[k][n] (f32) into MFMA A-fragment order, bf16:
// tile = kt*(Ntiles)+nt ; within tile: lane holds n = nt*16+(lane&15),
// k = kt*32+(lane>>4)*8+i, 8 contiguous bf16 per lane (one dwordx4).
__global__ __launch_bounds__(256) void repack_w(const float* __restrict__ src,
                                                __bf16* __restrict__ dst,
                                                int Kd, int Nsrc, int Ntiles) {
    int t = blockIdx.x * 256 + threadIdx.x;
    int total = (Kd >> 5) * Ntiles * 512;
    if (t >= total) return;
    int i    = t & 7;
    int lane = (t >> 3) & 63;
    int tile = t >> 9;
    int nt = tile % Ntiles;
    int kt = tile / Ntiles;
    int k = kt * 32 + ((lane >> 4) << 3) + i;
    int n = nt * 16 + (lane & 15);
    float v = (n < Nsrc) ? src[k * Nsrc + n] : 0.f;
    dst[t] = (__bf16)v;
}

// fast gelu (erf-form approximated by tanh; abs err ~2e-4, << bf16 noise)
__device__ __forceinline__ float gelu_f(float x) {
    float u = 0.7978845608f * (x + 0.044715f * x * x * x);
    float t = 1.f - 2.f / (__expf(2.f * u) + 1.f);   // tanh(u), saturates safely
    return 0.5f * x * (1.f + t);
}

// ---- fused GNN layer kernel ----
// One workgroup = 2 nodes (60 edges, padded to 64 rows). 8 waves; wave w owns
// output features [w*16, w*16+16). Computes Y^T = W^T X^T via MFMA so the
// accumulator lands with 4 consecutive n per lane at fixed edge-row m.

__device__ __forceinline__ void mm_part(f32x4 acc[4], const __bf16* __restrict__ wp,
                                        const __bf16* x, int sx, int ksteps,
                                        int wv, int lane) {
    const int mrow = lane & 15;
    const int kgrp = lane >> 4;
#pragma unroll
    for (int kt = 0; kt < ksteps; ++kt) {
        bf16x8 a = *reinterpret_cast<const bf16x8*>(wp + ((kt * 8 + wv) * 64 + lane) * 8);
        const int kb = kt * 32 + kgrp * 8;
#pragma unroll
        for (int mf = 0; mf < 4; ++mf) {
            bf16x8 b = *reinterpret_cast<const bf16x8*>(x + (mf * 16 + mrow) * sx + kb);
            acc[mf] = __builtin_amdgcn_mfma_f32_16x16x32_bf16(a, b, acc[mf], 0, 0, 0);
        }
    }
}

// actmode: 0 = relu, 1 = gelu, 2 = none
__device__ __forceinline__ void store_act(f32x4 acc[4], const float* __restrict__ bias,
                                          __bf16* y, int sy, int actmode,
                                          int wv, int lane) {
    const int mrow = lane & 15;
    const int kgrp = lane >> 4;
    const int nb = wv * 16 + kgrp * 4;
    const float* bp = bias + nb;
    float b0 = bp[0], b1 = bp[1], b2 = bp[2], b3 = bp[3];
#pragma unroll
    for (int mf = 0; mf < 4; ++mf) {
        bf16x4 pk;
        float vv[4] = {acc[mf][0] + b0, acc[mf][1] + b1, acc[mf][2] + b2, acc[mf][3] + b3};
#pragma unroll
        for (int r = 0; r < 4; ++r) {
            float v = vv[r];
            if (actmode == 0)      v = fmaxf(v, 0.f);
            else if (actmode == 1) v = gelu_f(v);
            pk[r] = (__bf16)v;
        }
        *reinterpret_cast<bf16x4*>(y + (mf * 16 + mrow) * sy + nb) = pk;
    }
}

__device__ __forceinline__ bf16x4 cvt4(float4 v) {
    bf16x4 r;
    r[0] = (__bf16)v.x; r[1] = (__bf16)v.y; r[2] = (__bf16)v.z; r[3] = (__bf16)v.w;
    return r;
}

#define ZERO_ACC(A)                                   \
    do {                                              \
        _Pragma("unroll")                             \
        for (int _m = 0; _m < 4; ++_m)                \
            A[_m] = (f32x4){0.f, 0.f, 0.f, 0.f};      \
    } while (0)

__global__ __launch_bounds__(512, 4) void gnn_fused(
    const float* __restrict__ h, const float* __restrict__ e, const int* __restrict__ eidx,
    const float* __restrict__ ab1, const float* __restrict__ ab2, const float* __restrict__ ab3,
    const float* __restrict__ nb1, const float* __restrict__ nb2, const float* __restrict__ nb3,
    const float* __restrict__ thw, const __bf16* __restrict__ wp, float* __restrict__ out) {

    // padded strides (+8 bf16) -> ~2-way LDS bank aliasing (free)
    __shared__ __bf16 sXB[64 * 264];   // [m][0:128)=e, [128:256)=hj
    __shared__ __bf16 sHI[64 * 136];   // hi; reused as att-Y2 and node-Y2
    __shared__ __bf16 sA1[64 * 136];   // att-Y1 / node-Y1 / V
    __shared__ float  sLog[64 * 4];    // logits [m][h]
    __shared__ float  sW[2 * 30 * 4];  // softmax weights per (node,k,h)
    __shared__ float  sPre[2][2][128]; // aggregated pre-projection (k-halves)
    __shared__ float  sAcc[2][2][128]; // projection partials (d-halves)

    const int tid  = threadIdx.x;
    const int wv   = tid >> 6;
    const int lane = tid & 63;
    const int node0 = blockIdx.x * 2;
    const long ebase = (long)node0 * KNEI;

    // ---- stage e, hj, hi rows (f32 -> bf16); pad rows 60..63 = 0 ----
#pragma unroll
    for (int c = 0; c < 4; ++c) {
        int idx = c * 512 + tid;
        int m  = idx >> 5;   // row 0..63
        int jv = idx & 31;   // float4 column
        float4 ev = make_float4(0.f, 0.f, 0.f, 0.f), hjv = ev, hiv = ev;
        if (m < 2 * KNEI) {
            long ge = ebase + m;
            ev  = *reinterpret_cast<const float4*>(e + ge * DIM + jv * 4);
            int dstn = eidx[EDGES + ge];
            hjv = *reinterpret_cast<const float4*>(h + (long)dstn * DIM + jv * 4);
            int srcn = eidx[ge];
            hiv = *reinterpret_cast<const float4*>(h + (long)srcn * DIM + jv * 4);
        }
        *reinterpret_cast<bf16x4*>(&sXB[m * 264 + jv * 4])       = cvt4(ev);
        *reinterpret_cast<bf16x4*>(&sXB[m * 264 + 128 + jv * 4]) = cvt4(hjv);
        *reinterpret_cast<bf16x4*>(&sHI[m * 136 + jv * 4])       = cvt4(hiv);
    }
    __syncthreads();

    f32x4 acc[4];

    // ---- att layer 1: [hi | e | hj] (K=384) -> relu -> sA1 ----
    ZERO_ACC(acc);
    mm_part(acc, wp + OFF_AW1,         sHI, 136, 4, wv, lane);  // k 0..127 (hi)
    mm_part(acc, wp + OFF_AW1 + 16384, sXB, 264, 8, wv, lane);  // k 128..383 (e|hj)
    store_act(acc, ab1, sA1, 136, 0, wv, lane);
    __syncthreads();

    // ---- att layer 2: sA1 -> relu -> sHI ----
    ZERO_ACC(acc);
    mm_part(acc, wp + OFF_AW2, sA1, 136, 4, wv, lane);
    store_act(acc, ab2, sHI, 136, 0, wv, lane);
    __syncthreads();

    // ---- att layer 3 (logits, 4 heads) on wave 0; other waves go to node1 ----
    if (wv == 0) {
        f32x4 a3[4];
#pragma unroll
        for (int mf = 0; mf < 4; ++mf) a3[mf] = (f32x4){0.f, 0.f, 0.f, 0.f};
        const int mrow = lane & 15, kgrp = lane >> 4;
#pragma unroll
        for (int kt = 0; kt < 4; ++kt) {
            bf16x8 aa = *reinterpret_cast<const bf16x8*>(wp + OFF_AW3 + (kt * 64 + lane) * 8);
            int kb = kt * 32 + kgrp * 8;
#pragma unroll
            for (int mf = 0; mf < 4; ++mf) {
                bf16x8 b = *reinterpret_cast<const bf16x8*>(sHI + (mf * 16 + mrow) * 136 + kb);
                a3[mf] = __builtin_amdgcn_mfma_f32_16x16x32_bf16(aa, b, a3[mf], 0, 0, 0);
            }
        }
        if (kgrp == 0) {  // lanes 0..15 hold h=0..3 in regs 0..3
            const float s = 0.17677669529f;  // 1/sqrt(32)
            float b0 = ab3[0], b1 = ab3[1], b2 = ab3[2], b3 = ab3[3];
#pragma unroll
            for (int mf = 0; mf < 4; ++mf) {
                float4 lg;
                lg.x = (a3[mf][0] + b0) * s;
                lg.y = (a3[mf][1] + b1) * s;
                lg.z = (a3[mf][2] + b2) * s;
                lg.w = (a3[mf][3] + b3) * s;
                *reinterpret_cast<float4*>(&sLog[(mf * 16 + mrow) * 4]) = lg;
            }
        }
    }

    // ---- node layer 1: [e | hj] (K=256) -> gelu -> sA1 ----
    ZERO_ACC(acc);
    mm_part(acc, wp + OFF_NW1, sXB, 264, 8, wv, lane);
    store_act(acc, nb1, sA1, 136, 1, wv, lane);
    __syncthreads();   // logits complete before sHI overwritten below

    // ---- node layer 2: sA1 -> gelu -> sHI ----
    ZERO_ACC(acc);
    mm_part(acc, wp + OFF_NW2, sA1, 136, 4, wv, lane);
    store_act(acc, nb2, sHI, 136, 1, wv, lane);
    __syncthreads();

    // softmax weights: per (node,head) max+sum+normalized exp into sW
    if (tid < 8) {
        int nd = tid >> 2, hh = tid & 3;
        float mx = -1e30f;
        for (int k = 0; k < KNEI; ++k) mx = fmaxf(mx, sLog[(nd * KNEI + k) * 4 + hh]);
        float sum = 0.f;
        for (int k = 0; k < KNEI; ++k) sum += __expf(sLog[(nd * KNEI + k) * 4 + hh] - mx);
        float inv = 1.f / sum;
        for (int k = 0; k < KNEI; ++k)
            sW[(nd * KNEI + k) * 4 + hh] = __expf(sLog[(nd * KNEI + k) * 4 + hh] - mx) * inv;
    }

    // ---- node layer 3: sHI -> (+bias, no act) -> V in sA1 ----
    ZERO_ACC(acc);
    mm_part(acc, wp + OFF_NW3, sHI, 136, 4, wv, lane);
    store_act(acc, nb3, sA1, 136, 2, wv, lane);
    __syncthreads();

    // ---- softmax-weighted aggregation, split over k-halves ----
    {
        int nd = tid >> 8, kh = (tid >> 7) & 1, dd = tid & 127, hh = dd >> 5;
        float a = 0.f;
#pragma unroll
        for (int kk = 0; kk < 15; ++kk) {
            int m = nd * KNEI + kh * 15 + kk;
            a += sW[m * 4 + hh] * (float)sA1[m * 136 + dd];
        }
        sPre[nd][kh][dd] = a;
    }
    __syncthreads();

    // ---- final projection: out = pre @ to_h_w, split over d-halves ----
    {
        int half = tid >> 8, nd = (tid >> 7) & 1, dd = tid & 127;
        float o = 0.f;
#pragma unroll 8
        for (int i = 0; i < 64; ++i) {
            int d = half * 64 + i;
            float p = sPre[nd][0][d] + sPre[nd][1][d];
            o += p * thw[d * DIM + dd];
        }
        sAcc[half][nd][dd] = o;
    }
    __syncthreads();

    if (tid < 256) {
        int nd = tid >> 7, dd = tid & 127;
        out[(long)(node0 + nd) * DIM + dd] = sAcc[0][nd][dd] + sAcc[1][nd][dd];
    }
}

extern "C" void kernel_launch(void* const* d_in, const int* in_sizes, int n_in,
                              void* d_out, int out_size, void* d_ws, size_t ws_size,
                              hipStream_t stream) {
    const float* h   = (const float*)d_in[0];
    const float* e   = (const float*)d_in[1];
    const int*   ei  = (const int*)d_in[2];
    const float* aw1 = (const float*)d_in[3];
    const float* ab1 = (const float*)d_in[4];
    const float* aw2 = (const float*)d_in[5];
    const float* ab2 = (const float*)d_in[6];
    const float* aw3 = (const float*)d_in[7];
    const float* ab3 = (const float*)d_in[8];
    const float* nw1 = (const float*)d_in[9];
    const float* nb1 = (const float*)d_in[10];
    const float* nw2 = (const float*)d_in[11];
    const float* nb2 = (const float*)d_in[12];
    const float* nw3 = (const float*)d_in[13];
    const float* nb3 = (const float*)d_in[14];
    const float* thw = (const float*)d_in[15];
    float* out = (float*)d_out;
    __bf16* wp = (__bf16*)d_ws;

    // weight repack (f32 -> bf16 MFMA-fragment order), ~266 KB into d_ws
    repack_w<<<192, 256, 0, stream>>>(aw1, wp + OFF_AW1, 384, 128, 8);
    repack_w<<<64,  256, 0, stream>>>(aw2, wp + OFF_AW2, 128, 128, 8);
    repack_w<<<8,   256, 0, stream>>>(aw3, wp + OFF_AW3, 128, 4,   1);
    repack_w<<<128, 256, 0, stream>>>(nw1, wp + OFF_NW1, 256, 128, 8);
    repack_w<<<64,  256, 0, stream>>>(nw2, wp + OFF_NW2, 128, 128, 8);
    repack_w<<<64,  256, 0, stream>>>(nw3, wp + OFF_NW3, 128, 128, 8);

    gnn_fused<<<N_NODES / 2, 512, 0, stream>>>(h, e, ei, ab1, ab2, ab3,
                                               nb1, nb2, nb3, thw, wp, out);
}